// Round 5
// baseline (449.619 us; speedup 1.0000x reference)
//
#include <hip/hip_runtime.h>

typedef unsigned int u32;
typedef unsigned short u16;
typedef __attribute__((ext_vector_type(8))) short bf16x8;   // 8 bf16 in 4 VGPRs
typedef __attribute__((ext_vector_type(4))) float f32x4;

#define DF 128
#define NBUCK 256          // max buckets (dst >> 9), N=100k -> 196 used
#define BUCK_SHIFT 9
#define BUCK_SIZE 512
#define P2_CHUNK 4096      // 16 edges per thread, 256 threads
#define NCOPY 16           // stat atomic spreading factor
#define STATW (NCOPY * DF)

__device__ __forceinline__ float bf2f(u32 h) { return __uint_as_float(h << 16); }
__device__ __forceinline__ u16 f2bf(float f) {
  u32 u = __float_as_uint(f);
  u32 r = (u + 0x7fffu + ((u >> 16) & 1u)) >> 16;   // RNE
  return (u16)r;
}
__device__ __forceinline__ u32 pack2(float a, float b) {
  return (u32)f2bf(a) | ((u32)f2bf(b) << 16);
}

// ---------- merged f32 -> bf16 conversion for x, W1, W2 (one dispatch) ----------
__global__ void k_cvt3(const float* __restrict__ x, const float* __restrict__ w1,
                       const float* __restrict__ w2, u16* __restrict__ xb,
                       u16* __restrict__ w1b, u16* __restrict__ w2b,
                       int n4x, int n4w) {
  int i = blockIdx.x * blockDim.x + threadIdx.x;
  const float* in; u16* out; int idx;
  if (i < n4x) { in = x; out = xb; idx = i; }
  else if (i < n4x + n4w) { in = w1; out = w1b; idx = i - n4x; }
  else if (i < n4x + 2 * n4w) { in = w2; out = w2b; idx = i - n4x - n4w; }
  else return;
  float4 v = ((const float4*)in)[idx];
  ((uint2*)out)[idx] = make_uint2(pack2(v.x, v.y), pack2(v.z, v.w));
}

// ---------- CSR build via bucketed counting sort ----------
__global__ __launch_bounds__(256) void k_p1(const int* __restrict__ dst,
                                            int* __restrict__ bucketCount, int E) {
  __shared__ int h[NBUCK];
  int t = threadIdx.x;
  h[t] = 0;
  __syncthreads();
  for (int e = blockIdx.x * 256 + t; e < E; e += gridDim.x * 256)
    atomicAdd(&h[((u32)dst[e]) >> BUCK_SHIFT], 1);
  __syncthreads();
  if (h[t]) atomicAdd(&bucketCount[t], h[t]);
}

__global__ __launch_bounds__(256) void k_pscan(const int* __restrict__ bucketCount,
                                               int* __restrict__ bucketStart,
                                               int* __restrict__ bucketCursor,
                                               int* __restrict__ rowptr, int N, int E) {
  __shared__ int sh[NBUCK];
  int t = threadIdx.x;
  int c = bucketCount[t];
  sh[t] = c;
  __syncthreads();
  for (int o = 1; o < 256; o <<= 1) {
    int v = (t >= o) ? sh[t - o] : 0;
    __syncthreads();
    sh[t] += v;
    __syncthreads();
  }
  int excl = sh[t] - c;
  bucketStart[t] = excl;
  bucketCursor[t] = excl;
  if (t == 255) { bucketStart[256] = sh[255]; rowptr[N] = E; }
}

__global__ __launch_bounds__(256) void k_p2(const int* __restrict__ src,
                                            const int* __restrict__ dst,
                                            int* __restrict__ bucketCursor,
                                            uint2* __restrict__ part, int E) {
  __shared__ int h[NBUCK], hs[NBUCK], base[NBUCK];
  __shared__ int total;
  __shared__ uint2 buf[P2_CHUNK];
  int t = threadIdx.x;
  int e0 = blockIdx.x * P2_CHUNK;
  h[t] = 0;
  __syncthreads();
  int myb[16], myr[16];
  uint2 mye[16];
  #pragma unroll
  for (int k = 0; k < 16; k++) {
    int e = e0 + k * 256 + t;
    myb[k] = -1;
    if (e < E) {
      int s = src[e], d = dst[e];
      mye[k] = make_uint2((u32)s, (u32)d);
      myb[k] = ((u32)d) >> BUCK_SHIFT;
      myr[k] = atomicAdd(&h[myb[k]], 1);
    }
  }
  __syncthreads();
  int hc = h[t];
  hs[t] = hc;
  __syncthreads();
  for (int o = 1; o < 256; o <<= 1) {
    int v = (t >= o) ? hs[t - o] : 0;
    __syncthreads();
    hs[t] += v;
    __syncthreads();
  }
  if (t == 255) total = hs[255];
  int excl = hs[t] - hc;
  base[t] = hc ? atomicAdd(&bucketCursor[t], hc) : 0;
  __syncthreads();
  hs[t] = excl;
  __syncthreads();
  #pragma unroll
  for (int k = 0; k < 16; k++)
    if (myb[k] >= 0) buf[hs[myb[k]] + myr[k]] = mye[k];
  __syncthreads();
  int tot = total;
  for (int i = t; i < tot; i += 256) {
    uint2 ed = buf[i];
    int b = ed.y >> BUCK_SHIFT;
    part[base[b] + (i - hs[b])] = ed;
  }
}

__global__ __launch_bounds__(256) void k_p3(const uint2* __restrict__ part,
                                            const int* __restrict__ bucketStart,
                                            int* __restrict__ rowptr,
                                            int* __restrict__ adj, int N) {
  __shared__ int deg[BUCK_SIZE], cur[BUCK_SIZE], psum[256];
  int b = blockIdx.x, t = threadIdx.x;
  int nodeBase = b << BUCK_SHIFT;
  int eb = bucketStart[b], ee = bucketStart[b + 1];
  deg[t] = 0; deg[t + 256] = 0;
  __syncthreads();
  for (int e = eb + t; e < ee; e += 256)
    atomicAdd(&deg[(int)part[e].y - nodeBase], 1);
  __syncthreads();
  int a0 = deg[2 * t], a1 = deg[2 * t + 1];
  psum[t] = a0 + a1;
  __syncthreads();
  for (int o = 1; o < 256; o <<= 1) {
    int v = (t >= o) ? psum[t - o] : 0;
    __syncthreads();
    psum[t] += v;
    __syncthreads();
  }
  int basep = psum[t] - (a0 + a1);
  int p0 = eb + basep, p1 = eb + basep + a0;
  cur[2 * t] = p0; cur[2 * t + 1] = p1;
  int n0 = nodeBase + 2 * t, n1 = nodeBase + 2 * t + 1;
  if (n0 < N) rowptr[n0] = p0;
  if (n1 < N) rowptr[n1] = p1;
  __syncthreads();
  for (int e = eb + t; e < ee; e += 256) {
    uint2 ed = part[e];
    int pos = atomicAdd(&cur[(int)ed.y - nodeBase], 1);
    adj[pos] = (int)ed.x;
  }
}

// ---------- aggregation: pure bf16 gather-sum, lo/hi packed-f32 accumulators ----------
// z = (1+eps)*h[n] + sum_{e:dst==n} msg(h[src]),  msg = doRelu? relu : identity
// one wave per node; 16 lanes per neighbor row (uint4 = 8 feats/lane), 2x unrolled.
// accLo holds feats {0,2,4,6}, accHi feats {1,3,5,7} of the lane's 8 -> v_pk_add_f32.
__global__ void k_aggr(const u16* __restrict__ h, const int* __restrict__ rowptr,
                       const int* __restrict__ adj, const float* __restrict__ epsArr,
                       int layer, int doRelu, u16* __restrict__ z, int N) {
  int wid = (blockIdx.x * blockDim.x + threadIdx.x) >> 6;
  if (wid >= N) return;
  int lane = threadIdx.x & 63;
  int g = lane >> 4, f = lane & 15;          // neighbor slot, feature group
  const uint4* h4 = (const uint4*)h;
  float e1 = 1.0f + epsArr[layer];

  f32x4 accLo = {0.f, 0.f, 0.f, 0.f}, accHi = {0.f, 0.f, 0.f, 0.f};

  // self term, group 0 only (no relu on self)
  if (g == 0) {
    uint4 v = h4[(size_t)wid * 16 + f];
    f32x4 lo = {__uint_as_float(v.x << 16), __uint_as_float(v.y << 16),
                __uint_as_float(v.z << 16), __uint_as_float(v.w << 16)};
    f32x4 hi = {__uint_as_float(v.x & 0xffff0000u), __uint_as_float(v.y & 0xffff0000u),
                __uint_as_float(v.z & 0xffff0000u), __uint_as_float(v.w & 0xffff0000u)};
    accLo = e1 * lo;
    accHi = e1 * hi;
  }

  int b = rowptr[wid], e = rowptr[wid + 1];
  for (int p = b; p < e; p += 8) {
    int i0 = p + g, i1 = p + 4 + g;
    uint4 v0 = make_uint4(0, 0, 0, 0), v1 = make_uint4(0, 0, 0, 0);
    if (i0 < e) v0 = h4[(size_t)(u32)adj[i0] * 16 + f];
    if (i1 < e) v1 = h4[(size_t)(u32)adj[i1] * 16 + f];
    u32 w0[4] = {v0.x, v0.y, v0.z, v0.w};
    u32 w1[4] = {v1.x, v1.y, v1.z, v1.w};
    if (doRelu) {
      #pragma unroll
      for (int k = 0; k < 4; k++) {
        u32 a = w0[k];
        if (a & 0x8000u)     a &= 0xffff0000u;
        if (a & 0x80000000u) a &= 0x0000ffffu;
        w0[k] = a;
        u32 bq = w1[k];
        if (bq & 0x8000u)     bq &= 0xffff0000u;
        if (bq & 0x80000000u) bq &= 0x0000ffffu;
        w1[k] = bq;
      }
    }
    f32x4 lo0 = {__uint_as_float(w0[0] << 16), __uint_as_float(w0[1] << 16),
                 __uint_as_float(w0[2] << 16), __uint_as_float(w0[3] << 16)};
    f32x4 hi0 = {__uint_as_float(w0[0] & 0xffff0000u), __uint_as_float(w0[1] & 0xffff0000u),
                 __uint_as_float(w0[2] & 0xffff0000u), __uint_as_float(w0[3] & 0xffff0000u)};
    f32x4 lo1 = {__uint_as_float(w1[0] << 16), __uint_as_float(w1[1] << 16),
                 __uint_as_float(w1[2] << 16), __uint_as_float(w1[3] << 16)};
    f32x4 hi1 = {__uint_as_float(w1[0] & 0xffff0000u), __uint_as_float(w1[1] & 0xffff0000u),
                 __uint_as_float(w1[2] & 0xffff0000u), __uint_as_float(w1[3] & 0xffff0000u)};
    accLo += lo0; accHi += hi0;
    accLo += lo1; accHi += hi1;
  }

  // reduce across the 4 neighbor slots
  #pragma unroll
  for (int k = 0; k < 4; k++) {
    accLo[k] += __shfl_xor(accLo[k], 16);
    accLo[k] += __shfl_xor(accLo[k], 32);
    accHi[k] += __shfl_xor(accHi[k], 16);
    accHi[k] += __shfl_xor(accHi[k], 32);
  }
  if (g == 0) {
    uint4 o = make_uint4(pack2(accLo[0], accHi[0]), pack2(accLo[1], accHi[1]),
                         pack2(accLo[2], accHi[2]), pack2(accLo[3], accHi[3]));
    ((uint4*)z)[(size_t)wid * 16 + f] = o;
  }
}

// ---------- GEMM, LDS-free: out[r][c] = sum_k in'[r][k]*W[c][k] + bias[c] ----------
// A/B MFMA fragments loaded directly from global (16B/lane; W L2-resident, A read once).
// trans: in' = relu(a[k]*in + c[k]) with BN coefs derived in-block from raw stats.
// stats out: per-wave shfl reduce -> atomics spread over NCOPY copies.
__global__ __launch_bounds__(256, 3) void k_gemm(
    const u16* __restrict__ A, const u16* __restrict__ W, const float* __restrict__ bias,
    const float* __restrict__ pS, const float* __restrict__ pQ,
    const float* __restrict__ gamma, const float* __restrict__ beta, int trans,
    float* __restrict__ statS, float* __restrict__ statQ,
    u16* __restrict__ out, int Nrows) {
  __shared__ float sA[DF], sC[DF];   // BN coefs (trans only), 1 KB
  int tid = threadIdx.x;
  if (trans) {
    if (tid < DF) {
      float S = 0.f, Q = 0.f;
      #pragma unroll
      for (int i = 0; i < NCOPY; i++) { S += pS[i * DF + tid]; Q += pQ[i * DF + tid]; }
      float inv_n = 1.0f / (float)Nrows;
      float mean = S * inv_n;
      float var = fmaxf(Q * inv_n - mean * mean, 0.0f);
      float iv = rsqrtf(var + 1e-5f);
      float av = gamma[tid] * iv;
      sA[tid] = av;
      sC[tid] = beta[tid] - mean * av;
    }
    __syncthreads();
  }

  int lane = tid & 63, w = tid >> 6;
  int rq = w >> 1, cq = w & 1;                 // wave -> 64x64 quadrant
  int m = lane & 15, quad = lane >> 4;
  int rowBase = blockIdx.x * 128;
  int lastRow = Nrows - 1;

  f32x4 acc[4][4];
  #pragma unroll
  for (int i = 0; i < 4; i++)
    #pragma unroll
    for (int j = 0; j < 4; j++) acc[i][j] = (f32x4){0.f, 0.f, 0.f, 0.f};

  #pragma unroll
  for (int kt = 0; kt < 4; kt++) {
    int gk = kt * 32 + quad * 8;
    bf16x8 af[4], bfr[4];
    #pragma unroll
    for (int i = 0; i < 4; i++) {
      int row = rowBase + (rq * 4 + i) * 16 + m;
      row = row < Nrows ? row : lastRow;       // clamp; invalid rows discarded at store
      af[i] = *(const bf16x8*)(A + (size_t)row * DF + gk);
    }
    #pragma unroll
    for (int j = 0; j < 4; j++)
      bfr[j] = *(const bf16x8*)(W + (size_t)((cq * 4 + j) * 16 + m) * DF + gk);
    if (trans) {
      f32x4 a0 = *(const f32x4*)(sA + gk), a1 = *(const f32x4*)(sA + gk + 4);
      f32x4 c0 = *(const f32x4*)(sC + gk), c1 = *(const f32x4*)(sC + gk + 4);
      #pragma unroll
      for (int i = 0; i < 4; i++) {
        bf16x8 v = af[i];
        #pragma unroll
        for (int k = 0; k < 8; k++) {
          float xk = __uint_as_float(((u32)(u16)v[k]) << 16);
          float ak = (k < 4) ? a0[k] : a1[k - 4];
          float ck = (k < 4) ? c0[k] : c1[k - 4];
          float r = fmaxf(fmaf(ak, xk, ck), 0.0f);
          v[k] = (short)f2bf(r);
        }
        af[i] = v;
      }
    }
    #pragma unroll
    for (int i = 0; i < 4; i++)
      #pragma unroll
      for (int j = 0; j < 4; j++)
        acc[i][j] = __builtin_amdgcn_mfma_f32_16x16x32_bf16(af[i], bfr[j], acc[i][j], 0, 0, 0);
  }

  // epilogue: bias, store bf16, per-column stats
  float colS[4] = {0, 0, 0, 0}, colQ[4] = {0, 0, 0, 0};
  #pragma unroll
  for (int j = 0; j < 4; j++) {
    int col = (cq * 4 + j) * 16 + m;
    float bv = bias[col];
    #pragma unroll
    for (int i = 0; i < 4; i++) {
      int row0 = rowBase + (rq * 4 + i) * 16 + quad * 4;
      #pragma unroll
      for (int r = 0; r < 4; r++) {
        int row = row0 + r;
        if (row < Nrows) {
          float v = acc[i][j][r] + bv;
          out[(size_t)row * DF + col] = f2bf(v);
          colS[j] += v;
          colQ[j] += v * v;
        }
      }
    }
  }
  int copyOff = (blockIdx.x & (NCOPY - 1)) * DF;
  #pragma unroll
  for (int j = 0; j < 4; j++) {
    float s = colS[j], q = colQ[j];
    s += __shfl_xor(s, 16); q += __shfl_xor(q, 16);
    s += __shfl_xor(s, 32); q += __shfl_xor(q, 32);
    if (quad == 0) {
      int col = (cq * 4 + j) * 16 + m;
      atomicAdd(&statS[copyOff + col], s);
      atomicAdd(&statQ[copyOff + col], q);
    }
  }
}

// ---------- BN apply with in-block coef derivation (bf16 out + relu) ----------
__global__ void k_bnapply_bf16(const u16* __restrict__ u, const float* __restrict__ pS,
                               const float* __restrict__ pQ, const float* __restrict__ gamma,
                               const float* __restrict__ beta, u16* __restrict__ h,
                               int n8, int Nrows) {
  __shared__ float sA[DF], sC[DF];
  int t = threadIdx.x;
  if (t < DF) {
    float S = 0.f, Q = 0.f;
    #pragma unroll
    for (int i = 0; i < NCOPY; i++) { S += pS[i * DF + t]; Q += pQ[i * DF + t]; }
    float inv_n = 1.0f / (float)Nrows;
    float mean = S * inv_n;
    float var = fmaxf(Q * inv_n - mean * mean, 0.0f);
    float iv = rsqrtf(var + 1e-5f);
    float av = gamma[t] * iv;
    sA[t] = av;
    sC[t] = beta[t] - mean * av;
  }
  __syncthreads();
  int i = blockIdx.x * blockDim.x + t;
  if (i >= n8) return;
  int col = (i * 8) & 127;
  f32x4 a0 = *(const f32x4*)(sA + col), a1v = *(const f32x4*)(sA + col + 4);
  f32x4 c0 = *(const f32x4*)(sC + col), c1v = *(const f32x4*)(sC + col + 4);
  uint4 v = ((const uint4*)u)[i];
  float f0 = fmaxf(fmaf(a0[0], bf2f(v.x & 0xffffu), c0[0]), 0.f);
  float f1 = fmaxf(fmaf(a0[1], bf2f(v.x >> 16),     c0[1]), 0.f);
  float f2 = fmaxf(fmaf(a0[2], bf2f(v.y & 0xffffu), c0[2]), 0.f);
  float f3 = fmaxf(fmaf(a0[3], bf2f(v.y >> 16),     c0[3]), 0.f);
  float f4 = fmaxf(fmaf(a1v[0], bf2f(v.z & 0xffffu), c1v[0]), 0.f);
  float f5 = fmaxf(fmaf(a1v[1], bf2f(v.z >> 16),     c1v[1]), 0.f);
  float f6 = fmaxf(fmaf(a1v[2], bf2f(v.w & 0xffffu), c1v[2]), 0.f);
  float f7 = fmaxf(fmaf(a1v[3], bf2f(v.w >> 16),     c1v[3]), 0.f);
  ((uint4*)h)[i] = make_uint4(pack2(f0, f1), pack2(f2, f3), pack2(f4, f5), pack2(f6, f7));
}

// ---------- BN apply, f32 out (final layer, no relu) ----------
__global__ void k_bnapply_f32(const u16* __restrict__ u, const float* __restrict__ pS,
                              const float* __restrict__ pQ, const float* __restrict__ gamma,
                              const float* __restrict__ beta, float* __restrict__ out,
                              int n8, int Nrows) {
  __shared__ float sA[DF], sC[DF];
  int t = threadIdx.x;
  if (t < DF) {
    float S = 0.f, Q = 0.f;
    #pragma unroll
    for (int i = 0; i < NCOPY; i++) { S += pS[i * DF + t]; Q += pQ[i * DF + t]; }
    float inv_n = 1.0f / (float)Nrows;
    float mean = S * inv_n;
    float var = fmaxf(Q * inv_n - mean * mean, 0.0f);
    float iv = rsqrtf(var + 1e-5f);
    float av = gamma[t] * iv;
    sA[t] = av;
    sC[t] = beta[t] - mean * av;
  }
  __syncthreads();
  int i = blockIdx.x * blockDim.x + t;
  if (i >= n8) return;
  int col = (i * 8) & 127;
  f32x4 a0 = *(const f32x4*)(sA + col), a1v = *(const f32x4*)(sA + col + 4);
  f32x4 c0 = *(const f32x4*)(sC + col), c1v = *(const f32x4*)(sC + col + 4);
  uint4 v = ((const uint4*)u)[i];
  float4 o0, o1;
  o0.x = fmaf(a0[0], bf2f(v.x & 0xffffu), c0[0]);
  o0.y = fmaf(a0[1], bf2f(v.x >> 16),     c0[1]);
  o0.z = fmaf(a0[2], bf2f(v.y & 0xffffu), c0[2]);
  o0.w = fmaf(a0[3], bf2f(v.y >> 16),     c0[3]);
  o1.x = fmaf(a1v[0], bf2f(v.z & 0xffffu), c1v[0]);
  o1.y = fmaf(a1v[1], bf2f(v.z >> 16),     c1v[1]);
  o1.z = fmaf(a1v[2], bf2f(v.w & 0xffffu), c1v[2]);
  o1.w = fmaf(a1v[3], bf2f(v.w >> 16),     c1v[3]);
  ((float4*)out)[i * 2] = o0;
  ((float4*)out)[i * 2 + 1] = o1;
}

extern "C" void kernel_launch(void* const* d_in, const int* in_sizes, int n_in,
                              void* d_out, int out_size, void* d_ws, size_t ws_size,
                              hipStream_t stream) {
  const float* x    = (const float*)d_in[0];
  const int*   ei   = (const int*)d_in[1];
  const float* W1   = (const float*)d_in[2];
  const float* b1   = (const float*)d_in[3];
  const float* g1   = (const float*)d_in[4];
  const float* bt1  = (const float*)d_in[5];
  const float* W2   = (const float*)d_in[6];
  const float* b2   = (const float*)d_in[7];
  const float* eps  = (const float*)d_in[8];
  const float* gout = (const float*)d_in[9];
  const float* btout= (const float*)d_in[10];

  int N = in_sizes[0] / DF;
  int E = in_sizes[1] / 2;
  int L = in_sizes[8];

  char* ws = (char*)d_ws;
  size_t off = 0;
  auto alloc = [&](size_t bytes) -> void* {
    void* p = ws + off;
    off += (bytes + 255) & ~(size_t)255;
    return p;
  };
  u16* Xb     = (u16*)alloc((size_t)N * DF * 2);
  u16* bufA   = (u16*)alloc((size_t)N * DF * 2);
  u16* bufB   = (u16*)alloc((size_t)N * DF * 2);
  int* rowptr = (int*)alloc((size_t)(N + 1) * 4);
  int* adj    = (int*)alloc((size_t)E * 4);
  uint2* part = (uint2*)alloc((size_t)E * 8);
  int* bCount = (int*)alloc(NBUCK * 4);
  int* bStart = (int*)alloc((NBUCK + 1) * 4);
  int* bCur   = (int*)alloc(NBUCK * 4);
  u16* W1b    = (u16*)alloc((size_t)L * DF * DF * 2);
  u16* W2b    = (u16*)alloc((size_t)L * DF * DF * 2);
  float* stats= (float*)alloc((size_t)L * 4 * STATW * 4);

  hipMemsetAsync(bCount, 0, NBUCK * 4, stream);
  hipMemsetAsync(stats, 0, (size_t)L * 4 * STATW * 4, stream);

  int n4x = N * DF / 4;
  int n4w = L * DF * DF / 4;
  int n4tot = n4x + 2 * n4w;
  k_cvt3<<<(n4tot + 255) / 256, 256, 0, stream>>>(x, W1, W2, Xb, W1b, W2b, n4x, n4w);

  const int* srcI = ei;
  const int* dstI = ei + E;
  int nbuckets = (N + BUCK_SIZE - 1) >> BUCK_SHIFT;
  k_p1<<<512, 256, 0, stream>>>(dstI, bCount, E);
  k_pscan<<<1, 256, 0, stream>>>(bCount, bStart, bCur, rowptr, N, E);
  k_p2<<<(E + P2_CHUNK - 1) / P2_CHUNK, 256, 0, stream>>>(srcI, dstI, bCur, part, E);
  k_p3<<<nbuckets, 256, 0, stream>>>(part, bStart, rowptr, adj, N);

  // Per layer: aggr: H -> bufA ; gemm1: bufA -> bufB (stats1) ;
  //            gemm2(BN1+relu fused on load): bufB -> bufA (stats2) ;
  //            bnapply(BN2 [+relu]): bufA -> bufB (=H next) / d_out (f32 final)
  int gblocks = (N + 127) / 128;
  int n8 = N * DF / 8;
  for (int l = 0; l < L; l++) {
    float* S1 = stats + (size_t)(l * 4 + 0) * STATW;
    float* Q1 = stats + (size_t)(l * 4 + 1) * STATW;
    float* S2 = stats + (size_t)(l * 4 + 2) * STATW;
    float* Q2 = stats + (size_t)(l * 4 + 3) * STATW;
    const u16* H = (l == 0) ? Xb : bufB;
    k_aggr<<<(N + 3) / 4, 256, 0, stream>>>(H, rowptr, adj, eps, l,
                                            (l == 0) ? 1 : 0, bufA, N);
    k_gemm<<<gblocks, 256, 0, stream>>>(bufA, W1b + l * DF * DF, b1 + l * DF,
                                        nullptr, nullptr, nullptr, nullptr, 0,
                                        S1, Q1, bufB, N);
    k_gemm<<<gblocks, 256, 0, stream>>>(bufB, W2b + l * DF * DF, b2 + l * DF,
                                        S1, Q1, g1 + l * DF, bt1 + l * DF, 1,
                                        S2, Q2, bufA, N);
    if (l < L - 1) {
      k_bnapply_bf16<<<(n8 + 255) / 256, 256, 0, stream>>>(
          bufA, S2, Q2, gout + l * DF, btout + l * DF, bufB, n8, N);
    } else {
      k_bnapply_f32<<<(n8 + 255) / 256, 256, 0, stream>>>(
          bufA, S2, Q2, gout + l * DF, btout + l * DF, (float*)d_out, n8, N);
    }
  }
}